// Round 3
// baseline (264.670 us; speedup 1.0000x reference)
//
#include <hip/hip_runtime.h>

// Causal cumulative mean over time: out[b,t,c] = (1/(t+1)) * sum_{s<=t} x[b,s,c]
// x: (B=8, T=4096, C=1024) fp32. Two-pass chunked scan:
//   Pass A: partial[b][k][c] = sum of x over chunk k (CHUNK=64 time steps)
//   Pass B: per-chunk block sums preceding partials (L2-resident, 2MB) then
//           does the in-chunk running prefix and writes out / (t+1).
// Each thread owns 4 consecutive channels via float4 -> coalesced 16B/lane.

constexpr int B_SZ   = 8;
constexpr int T_SZ   = 4096;
constexpr int C_SZ   = 1024;
constexpr int CHUNK  = 64;
constexpr int NCHUNK = T_SZ / CHUNK;   // 64
constexpr int C4     = C_SZ / 4;       // 256 threads/block

__global__ __launch_bounds__(C4) void cummean_partial(
    const float4* __restrict__ x, float4* __restrict__ part) {
    const int k = blockIdx.x;   // chunk
    const int b = blockIdx.y;   // batch
    const int c = threadIdx.x;  // float4 channel index

    const float4* xp = x + (size_t)(b * T_SZ + k * CHUNK) * C4 + c;
    float4 s = make_float4(0.f, 0.f, 0.f, 0.f);
#pragma unroll 8
    for (int t = 0; t < CHUNK; ++t) {
        float4 v = xp[(size_t)t * C4];
        s.x += v.x; s.y += v.y; s.z += v.z; s.w += v.w;
    }
    part[(size_t)(b * NCHUNK + k) * C4 + c] = s;
}

__global__ __launch_bounds__(C4) void cummean_scan(
    const float4* __restrict__ x, const float4* __restrict__ part,
    float4* __restrict__ out) {
    const int k = blockIdx.x;
    const int b = blockIdx.y;
    const int c = threadIdx.x;

    // Exclusive prefix of chunk partials (partial array is 2MB -> cache hits)
    float4 run = make_float4(0.f, 0.f, 0.f, 0.f);
    const float4* pp = part + (size_t)b * NCHUNK * C4 + c;
    for (int j = 0; j < k; ++j) {
        float4 v = pp[(size_t)j * C4];
        run.x += v.x; run.y += v.y; run.z += v.z; run.w += v.w;
    }

    const size_t base = (size_t)(b * T_SZ + k * CHUNK) * C4 + c;
    const float4* xp = x + base;
    float4*       op = out + base;
    const int t0 = k * CHUNK;
#pragma unroll 4
    for (int t = 0; t < CHUNK; ++t) {
        float4 v = xp[(size_t)t * C4];
        run.x += v.x; run.y += v.y; run.z += v.z; run.w += v.w;
        const float inv = 1.0f / (float)(t0 + t + 1);
        float4 o;
        o.x = run.x * inv; o.y = run.y * inv; o.z = run.z * inv; o.w = run.w * inv;
        op[(size_t)t * C4] = o;
    }
}

extern "C" void kernel_launch(void* const* d_in, const int* in_sizes, int n_in,
                              void* d_out, int out_size, void* d_ws, size_t ws_size,
                              hipStream_t stream) {
    const float4* x   = (const float4*)d_in[0];
    float4*       out = (float4*)d_out;
    float4*       part = (float4*)d_ws;   // B*NCHUNK*C floats = 2 MB

    dim3 grid(NCHUNK, B_SZ);
    cummean_partial<<<grid, C4, 0, stream>>>(x, part);
    cummean_scan<<<grid, C4, 0, stream>>>(x, part, out);
}